// Round 1
// baseline (312.428 us; speedup 1.0000x reference)
//
#include <hip/hip_runtime.h>
#include <hip/hip_bf16.h>
#include <stdint.h>

#define B_ 4
#define K_ 4
#define V_ 32
#define D_ 64
#define H_ 4
#define S_ 1024
#define BK_ 16
#define SCALE 0.25f

typedef __attribute__((ext_vector_type(8))) short bf16x8;
typedef __attribute__((ext_vector_type(4))) float f32x4;
typedef __attribute__((ext_vector_type(16))) float f32x16;

// ---------------------------------------------------------------- W repack
// W[o][i][t] (15 floats/row) -> W2[o][16] padded (b128-friendly)
__global__ __launch_bounds__(256) void prep_w2_kernel(const float* __restrict__ W,
                                                      float* __restrict__ W2) {
    int idx = blockIdx.x * 256 + threadIdx.x;   // 24576*16 threads
    int o = idx >> 4, j = idx & 15;
    W2[idx] = (j < 15) ? W[o * 15 + j] : 0.f;
}

// ---------------------------------------------------------------- conv (fp32 -> bf16 qkv)
// qkv layout (bf16): [bk][sl][c3][v][d]  (6144 contiguous per (bk,sl))
// block: (bk, c3, vgroup-of-8, sl-tile-of-32); thread: 2 channels x 32 sl
__global__ __launch_bounds__(256) void conv_kernel(const float* __restrict__ x,
                                                   const float* __restrict__ W2,
                                                   const float* __restrict__ bias,
                                                   __hip_bfloat16* __restrict__ qkv,
                                                   int SC, int s0, int ntile) {
    int blk = blockIdx.x;
    int tile = blk % ntile; blk /= ntile;
    int vg = blk & 3; blk >>= 2;
    int c3 = blk % 3; int bk = blk / 3;
    int b = bk >> 2, k = bk & 3;
    int sl0 = tile * 32;
    int sg0 = s0 + sl0;
    int t = threadIdx.x;

    __shared__ float xs[24][36];          // 8 v * 3 in-ch, 32+4 s window
    __shared__ unsigned out_s[32][256];   // [sl][c/2] packed bf16x2  (32KB)

    for (int i = t; i < 24 * 36; i += 256) {
        int row = i / 36, col = i % 36;
        int vr = row / 3, ii = row % 3;
        int g = k * V_ + vg * 8 + vr;
        int s = sg0 - 4 + col;
        xs[row][col] = (s >= 0) ? x[((size_t)b * 384 + g * 3 + ii) * S_ + s] : 0.f;
    }
    __syncthreads();

    int c0 = 2 * t;
    int vr = c0 >> 6;
    int d0 = c0 & 63;
    int g = k * V_ + vg * 8 + vr;
    int obase = (g * 3 + c3) * 64;

    float w0[16], w1[16];
    {
        const float4* p0 = (const float4*)(W2 + (size_t)(obase + d0) * 16);
        const float4* p1 = (const float4*)(W2 + (size_t)(obase + d0 + 1) * 16);
        #pragma unroll
        for (int j = 0; j < 4; ++j) {
            float4 a = p0[j], c = p1[j];
            w0[4 * j] = a.x; w0[4 * j + 1] = a.y; w0[4 * j + 2] = a.z; w0[4 * j + 3] = a.w;
            w1[4 * j] = c.x; w1[4 * j + 1] = c.y; w1[4 * j + 2] = c.z; w1[4 * j + 3] = c.w;
        }
    }
    float bias0 = bias[obase + d0], bias1 = bias[obase + d0 + 1];

    #pragma unroll
    for (int slb = 0; slb < 4; ++slb) {
        float xw[3][12];
        #pragma unroll
        for (int ii = 0; ii < 3; ++ii)
            #pragma unroll
            for (int j = 0; j < 12; ++j)
                xw[ii][j] = xs[vr * 3 + ii][slb * 8 + j];
        #pragma unroll
        for (int s8 = 0; s8 < 8; ++s8) {
            float a0 = bias0, a1 = bias1;
            #pragma unroll
            for (int ii = 0; ii < 3; ++ii)
                #pragma unroll
                for (int tt = 0; tt < 5; ++tt) {
                    float xv = xw[ii][s8 + tt];
                    a0 = fmaf(xv, w0[ii * 5 + tt], a0);
                    a1 = fmaf(xv, w1[ii * 5 + tt], a1);
                }
            unsigned pk;
            asm("v_cvt_pk_bf16_f32 %0, %1, %2" : "=v"(pk) : "v"(a0), "v"(a1));
            out_s[slb * 8 + s8][t] = pk;
        }
    }
    __syncthreads();

    size_t gb = (size_t)(bk * SC + sl0) * 6144 + (size_t)(c3 * 2048 + vg * 512);
    #pragma unroll
    for (int j = 0; j < 8; ++j) {
        int idx = j * 256 + t;
        int sl = idx >> 6, cc = idx & 63;
        uint4 val = *(const uint4*)&out_s[sl][cc * 4];
        *(uint4*)(qkv + gb + (size_t)sl * 6144 + cc * 8) = val;
    }
}

// ---------------------------------------------------------------- attention (bf16 MFMA)
// one wave per (bk, s); h looped inside (attn-mean accumulates in regs)
// writes: xo_ws f32 [bk][sl][h][qv][dk16] ; attn_ws f32 [bk][sl][qv][kv] (already /4)
__global__ __launch_bounds__(256) void attn_kernel(const __hip_bfloat16* __restrict__ qkv,
                                                   float* __restrict__ attn_ws,
                                                   float* __restrict__ xo_ws, int SC) {
    int nquad = SC >> 2;
    int bk = blockIdx.x / nquad;
    int sl0 = (blockIdx.x % nquad) << 2;
    int t = threadIdx.x;
    int wid = t >> 6, lane = t & 63;
    int l31 = lane & 31, hi2 = lane >> 5;
    int l15 = lane & 15, hi4 = lane >> 4;

    __shared__ __align__(16) unsigned short vT[4][16][40];   // [sl][d][kv] (padded)
    __shared__ __align__(16) unsigned short pT[4][32][40];   // [wave][qv][kv] (padded)

    float acc_am[16];
    #pragma unroll
    for (int r = 0; r < 16; ++r) acc_am[r] = 0.f;

    size_t base = (size_t)bk * SC + sl0;

    int s_sl = t >> 6, s_v = (t >> 1) & 31, s_dh = t & 1;

    for (int h = 0; h < 4; ++h) {
        __syncthreads();
        {   // stage V transposed: vT[sl][d][kv]
            uint4 val = *(const uint4*)(qkv + (((base + s_sl) * 3 + 2) * 32 + s_v) * 64
                                        + h * 16 + s_dh * 8);
            const unsigned short* us = (const unsigned short*)&val;
            #pragma unroll
            for (int j = 0; j < 8; ++j)
                vT[s_sl][s_dh * 8 + j][s_v] = us[j];
        }
        __syncthreads();

        // logits = K * Q^T : D[kv][qv], A-frag: row=l&31, k=(l>>5)*8.. ; B-frag: col=l&31
        bf16x8 qf = *(const bf16x8*)(qkv + (((base + wid) * 3 + 0) * 32 + l31) * 64
                                     + h * 16 + hi2 * 8);
        bf16x8 kf = *(const bf16x8*)(qkv + (((base + wid) * 3 + 1) * 32 + l31) * 64
                                     + h * 16 + hi2 * 8);
        f32x16 zc;
        #pragma unroll
        for (int i = 0; i < 16; ++i) zc[i] = 0.f;
        f32x16 lg = __builtin_amdgcn_mfma_f32_32x32x16_bf16(kf, qf, zc, 0, 0, 0);

        // softmax over kv: lane holds 16 rows (kv=(r&3)+8*(r>>2)+4*hi2) of column qv=l31
        float p[16], m = -3.0e38f;
        #pragma unroll
        for (int r = 0; r < 16; ++r) { p[r] = lg[r] * SCALE; m = fmaxf(m, p[r]); }
        m = fmaxf(m, __shfl_xor(m, 32));
        float ssum = 0.f;
        #pragma unroll
        for (int r = 0; r < 16; ++r) { p[r] = __expf(p[r] - m); ssum += p[r]; }
        ssum += __shfl_xor(ssum, 32);
        float inv = 1.f / ssum;
        #pragma unroll
        for (int r = 0; r < 16; ++r) { p[r] *= inv; acc_am[r] += p[r]; }

        // pack P -> pT[qv][kv] bf16 (pairs of consecutive kv)
        unsigned* pTrow = (unsigned*)&pT[wid][l31][0];
        #pragma unroll
        for (int mm = 0; mm < 8; ++mm) {
            unsigned pk;
            asm("v_cvt_pk_bf16_f32 %0, %1, %2" : "=v"(pk) : "v"(p[2 * mm]), "v"(p[2 * mm + 1]));
            pTrow[(mm & 1) + 4 * (mm >> 1) + 2 * hi2] = pk;
        }

        // PV: xo^T[d][qv] = V^T * P^T ; A=vT row d=l&15, kv=(l>>4)*8.. ; B=pT row qv
        bf16x8 vf = *(const bf16x8*)&vT[wid][l15][hi4 * 8];
        bf16x8 p1 = *(const bf16x8*)&pT[wid][l15][hi4 * 8];
        bf16x8 p2 = *(const bf16x8*)&pT[wid][16 + l15][hi4 * 8];
        f32x4 z4;
        #pragma unroll
        for (int i = 0; i < 4; ++i) z4[i] = 0.f;
        f32x4 xo1 = __builtin_amdgcn_mfma_f32_16x16x32_bf16(vf, p1, z4, 0, 0, 0);
        f32x4 xo2 = __builtin_amdgcn_mfma_f32_16x16x32_bf16(vf, p2, z4, 0, 0, 0);

        // D: col(l&15)=qv, row((l>>4)*4+r)=d -> 4 consecutive d per reg group
        float* xob = xo_ws + ((base + wid) * 4 + h) * 512;
        *(f32x4*)(xob + l15 * 16 + hi4 * 4) = xo1;
        *(f32x4*)(xob + (size_t)(16 + l15) * 16 + hi4 * 4) = xo2;
    }

    float* ab = attn_ws + (base + wid) * 1024 + l31 * 32;
    #pragma unroll
    for (int mm = 0; mm < 8; ++mm) {
        int kvh = 2 * (mm & 1) + 8 * (mm >> 1) + 4 * hi2;
        float2 v; v.x = 0.25f * acc_am[2 * mm]; v.y = 0.25f * acc_am[2 * mm + 1];
        *(float2*)(ab + kvh) = v;
    }
}

// ---------------------------------------------------------------- xo transpose to [b][c][s]
// block: (bk, h, qv-quad, sl-tile-32); tile [32 sl][64 cols=(4qv x 16dk)]
__global__ __launch_bounds__(256) void cxo_kernel(const float* __restrict__ xo_ws,
                                                  float* __restrict__ out, int SC, int s0) {
    int blk = blockIdx.x;
    int nt = SC >> 5;
    int tile = blk % nt; blk /= nt;
    int qvq = blk & 7; blk >>= 3;
    int h = blk & 3; int bk = blk >> 2;
    int b = bk >> 2, k = bk & 3;
    int t = threadIdx.x;
    int sl_base = tile * 32;
    int qv0 = qvq * 4;

    __shared__ float ts[64][33];

    {
        int col = t & 63, sl = t >> 6;
        #pragma unroll
        for (int j = 0; j < 8; ++j) {
            int sll = sl + j * 4;
            ts[col][sll] = xo_ws[(((size_t)bk * SC + sl_base + sll) * 4 + h) * 512
                                 + qv0 * 16 + col];
        }
    }
    __syncthreads();
    {
        int sl = t & 31, cq = t >> 5;
        #pragma unroll
        for (int j = 0; j < 8; ++j) {
            int col = cq + j * 8;
            int c = (k * V_ + qv0 + (col >> 4)) * 64 + h * 16 + (col & 15);
            out[((size_t)b * 8192 + c) * S_ + s0 + sl_base + sl] = ts[col][sl];
        }
    }
}

// ---------------------------------------------------------------- attn_m transpose
// block: (bk, p-tile-64, sl-tile-32); in [bk][sl][p=qv*32+kv] -> out [bk][p][s]
__global__ __launch_bounds__(256) void cattn_kernel(const float* __restrict__ attn_ws,
                                                    float* __restrict__ out_am, int SC, int s0) {
    int blk = blockIdx.x;
    int nt = SC >> 5;
    int tile = blk % nt; blk /= nt;
    int pt = blk & 15; int bk = blk >> 4;
    int t = threadIdx.x;
    int sl_base = tile * 32, p0 = pt * 64;

    __shared__ float ts[32][65];

    {
        int p = t & 63, sl = t >> 6;
        #pragma unroll
        for (int j = 0; j < 8; ++j) {
            int sll = sl + j * 4;
            ts[sll][p] = attn_ws[((size_t)bk * SC + sl_base + sll) * 1024 + p0 + p];
        }
    }
    __syncthreads();
    {
        int sl = t & 31, pq = t >> 5;
        #pragma unroll
        for (int j = 0; j < 8; ++j) {
            int p = pq + j * 8;
            out_am[((size_t)bk * 1024 + p0 + p) * S_ + s0 + sl_base + sl] = ts[sl][p];
        }
    }
}

// ---------------------------------------------------------------- launch
extern "C" void kernel_launch(void* const* d_in, const int* in_sizes, int n_in,
                              void* d_out, int out_size, void* d_ws, size_t ws_size,
                              hipStream_t stream) {
    const float* x = (const float*)d_in[0];
    const float* W = (const float*)d_in[1];
    const float* bias = (const float*)d_in[2];
    float* out = (float*)d_out;
    float* out_am = out + (size_t)33554432;   // xo is 4*8192*1024

    const size_t W2_BYTES = (size_t)24576 * 16 * 4;
    // chunk size SC over S: per-chunk ws = 393216*SC bytes
    int SC = 32;
    for (int cand = 256; cand >= 32; cand >>= 1) {
        size_t need = W2_BYTES + (size_t)393216 * cand;
        if (need <= ws_size) { SC = cand; break; }
    }

    char* pw = (char*)d_ws;
    float* W2 = (float*)pw;
    char* pc = pw + W2_BYTES;
    __hip_bfloat16* qkv = (__hip_bfloat16*)pc;
    size_t QKV_BYTES = (size_t)16 * SC * 6144 * 2;
    float* attn_ws = (float*)(pc + QKV_BYTES);
    size_t ATTN_BYTES = (size_t)16 * SC * 1024 * 4;
    float* xo_ws = (float*)(pc + QKV_BYTES + ATTN_BYTES);

    prep_w2_kernel<<<1536, 256, 0, stream>>>(W, W2);

    int ntile = SC / 32;
    for (int s0 = 0; s0 < S_; s0 += SC) {
        conv_kernel<<<dim3(16 * 3 * 4 * ntile), 256, 0, stream>>>(x, W2, bias, qkv, SC, s0, ntile);
        attn_kernel<<<dim3(16 * (SC / 4)), 256, 0, stream>>>(qkv, attn_ws, xo_ws, SC);
        cxo_kernel<<<dim3(16 * 4 * 8 * ntile), 256, 0, stream>>>(xo_ws, out, SC, s0);
        cattn_kernel<<<dim3(16 * 16 * ntile), 256, 0, stream>>>(attn_ws, out_am, SC, s0);
    }
}

// Round 2
// 229.584 us; speedup vs baseline: 1.3608x; 1.3608x over previous
//
#include <hip/hip_runtime.h>
#include <hip/hip_bf16.h>
#include <stdint.h>

#define B_ 4
#define K_ 4
#define V_ 32
#define D_ 64
#define H_ 4
#define S_ 1024
#define BK_ 16
#define SCALE 0.25f

typedef __attribute__((ext_vector_type(8))) short bf16x8;
typedef __attribute__((ext_vector_type(4))) float f32x4;
typedef __attribute__((ext_vector_type(16))) float f32x16;

// ---------------------------------------------------------------- W repack
// W[o][i][t] (15 floats/row) -> W2[o][16] padded (b128-friendly)
__global__ __launch_bounds__(256) void prep_w2_kernel(const float* __restrict__ W,
                                                      float* __restrict__ W2) {
    int idx = blockIdx.x * 256 + threadIdx.x;   // 24576*16 threads
    int o = idx >> 4, j = idx & 15;
    W2[idx] = (j < 15) ? W[o * 15 + j] : 0.f;
}

// ---------------------------------------------------------------- conv (fp32 -> bf16 qkv)
// qkv layout (bf16): [bk][sl][c3][v][d]  (6144 contiguous per (bk,sl))
// block: (bk, c3, vgroup-of-8, sl-tile-of-32); thread: 2 channels x 32 sl
__global__ __launch_bounds__(256) void conv_kernel(const float* __restrict__ x,
                                                   const float* __restrict__ W2,
                                                   const float* __restrict__ bias,
                                                   __hip_bfloat16* __restrict__ qkv,
                                                   int SC, int s0, int ntile) {
    int blk = blockIdx.x;
    int tile = blk % ntile; blk /= ntile;
    int vg = blk & 3; blk >>= 2;
    int c3 = blk % 3; int bk = blk / 3;
    int b = bk >> 2, k = bk & 3;
    int sl0 = tile * 32;
    int sg0 = s0 + sl0;
    int t = threadIdx.x;

    __shared__ float xs[24][36];          // 8 v * 3 in-ch, 32+4 s window
    __shared__ unsigned out_s[32][256];   // [sl][c/2] packed bf16x2  (32KB)

    for (int i = t; i < 24 * 36; i += 256) {
        int row = i / 36, col = i % 36;
        int vr = row / 3, ii = row % 3;
        int g = k * V_ + vg * 8 + vr;
        int s = sg0 - 4 + col;
        xs[row][col] = (s >= 0) ? x[((size_t)b * 384 + g * 3 + ii) * S_ + s] : 0.f;
    }
    __syncthreads();

    int c0 = 2 * t;
    int vr = c0 >> 6;
    int d0 = c0 & 63;
    int g = k * V_ + vg * 8 + vr;
    int obase = (g * 3 + c3) * 64;

    float w0[16], w1[16];
    {
        const float4* p0 = (const float4*)(W2 + (size_t)(obase + d0) * 16);
        const float4* p1 = (const float4*)(W2 + (size_t)(obase + d0 + 1) * 16);
        #pragma unroll
        for (int j = 0; j < 4; ++j) {
            float4 a = p0[j], c = p1[j];
            w0[4 * j] = a.x; w0[4 * j + 1] = a.y; w0[4 * j + 2] = a.z; w0[4 * j + 3] = a.w;
            w1[4 * j] = c.x; w1[4 * j + 1] = c.y; w1[4 * j + 2] = c.z; w1[4 * j + 3] = c.w;
        }
    }
    float bias0 = bias[obase + d0], bias1 = bias[obase + d0 + 1];

    #pragma unroll
    for (int slb = 0; slb < 4; ++slb) {
        float xw[3][12];
        #pragma unroll
        for (int ii = 0; ii < 3; ++ii)
            #pragma unroll
            for (int j = 0; j < 12; ++j)
                xw[ii][j] = xs[vr * 3 + ii][slb * 8 + j];
        #pragma unroll
        for (int s8 = 0; s8 < 8; ++s8) {
            float a0 = bias0, a1 = bias1;
            #pragma unroll
            for (int ii = 0; ii < 3; ++ii)
                #pragma unroll
                for (int tt = 0; tt < 5; ++tt) {
                    float xv = xw[ii][s8 + tt];
                    a0 = fmaf(xv, w0[ii * 5 + tt], a0);
                    a1 = fmaf(xv, w1[ii * 5 + tt], a1);
                }
            unsigned pk;
            asm("v_cvt_pk_bf16_f32 %0, %1, %2" : "=v"(pk) : "v"(a0), "v"(a1));
            out_s[slb * 8 + s8][t] = pk;
        }
    }
    __syncthreads();

    size_t gb = (size_t)(bk * SC + sl0) * 6144 + (size_t)(c3 * 2048 + vg * 512);
    #pragma unroll
    for (int j = 0; j < 8; ++j) {
        int idx = j * 256 + t;
        int sl = idx >> 6, cc = idx & 63;
        uint4 val = *(const uint4*)&out_s[sl][cc * 4];
        *(uint4*)(qkv + gb + (size_t)sl * 6144 + cc * 8) = val;
    }
}

// ---------------------------------------------------------------- fused attention + output
// block = (bk, 16 s); 4 waves, wave w computes s_loc = w*4+si, si=0..3, per h.
// Per-wave private vT/pT staging (no barriers in compute). Outputs written
// directly in final [c][s]-major layout via LDS tiles + coalesced sweeps.
__global__ __launch_bounds__(256) void attn2_kernel(const __hip_bfloat16* __restrict__ qkv,
                                                    float* __restrict__ out,
                                                    float* __restrict__ out_am,
                                                    int SC, int s0) {
    int nst = SC >> 4;
    int st = blockIdx.x % nst;
    int bk = blockIdx.x / nst;
    int b = bk >> 2, k_ = bk & 3;
    int stile0 = st << 4;                   // chunk-local s base
    int t = threadIdx.x;
    int wid = t >> 6, lane = t & 63;
    int l31 = lane & 31, hi2 = lane >> 5;
    int l15 = lane & 15, hi4 = lane >> 4;

    __shared__ __align__(16) float smem[16 * 516];            // xo tile [16 s][516]; reused as att_t[512][16]
    __shared__ __align__(16) unsigned short vT[4][16][40];    // per-wave [d16][kv32+pad]
    __shared__ __align__(16) unsigned short pT[4][32][40];    // per-wave [qv32][kv32+pad]

    float acc[4][16];
    #pragma unroll
    for (int si = 0; si < 4; ++si)
        #pragma unroll
        for (int r = 0; r < 16; ++r) acc[si][r] = 0.f;

    size_t base = (size_t)bk * SC + stile0;

    for (int h = 0; h < 4; ++h) {
        // prefetch si=0
        bf16x8 q_c, k_c; uint4 v_c;
        {
            size_t sg = base + wid * 4;
            q_c = *(const bf16x8*)(qkv + ((sg * 3 + 0) * 32 + l31) * 64 + h * 16 + hi2 * 8);
            k_c = *(const bf16x8*)(qkv + ((sg * 3 + 1) * 32 + l31) * 64 + h * 16 + hi2 * 8);
            v_c = *(const uint4*)(qkv + ((sg * 3 + 2) * 32 + l31) * 64 + h * 16 + hi2 * 8);
        }
        #pragma unroll
        for (int si = 0; si < 4; ++si) {
            bf16x8 q_n, k_n; uint4 v_n;
            if (si < 3) {
                size_t sg = base + wid * 4 + si + 1;
                q_n = *(const bf16x8*)(qkv + ((sg * 3 + 0) * 32 + l31) * 64 + h * 16 + hi2 * 8);
                k_n = *(const bf16x8*)(qkv + ((sg * 3 + 1) * 32 + l31) * 64 + h * 16 + hi2 * 8);
                v_n = *(const uint4*)(qkv + ((sg * 3 + 2) * 32 + l31) * 64 + h * 16 + hi2 * 8);
            }
            // stage V transposed (per-wave): vT[d][kv]
            {
                const unsigned short* us = (const unsigned short*)&v_c;
                #pragma unroll
                for (int j = 0; j < 8; ++j)
                    vT[wid][hi2 * 8 + j][l31] = us[j];
            }
            // logits = K * Q^T : D[kv][qv]
            f32x16 zc;
            #pragma unroll
            for (int i = 0; i < 16; ++i) zc[i] = 0.f;
            f32x16 lg = __builtin_amdgcn_mfma_f32_32x32x16_bf16(k_c, q_c, zc, 0, 0, 0);

            // softmax over kv (lane holds 16 kv-rows of column qv=l31)
            float p[16], m = -3.0e38f;
            #pragma unroll
            for (int r = 0; r < 16; ++r) { p[r] = lg[r] * SCALE; m = fmaxf(m, p[r]); }
            m = fmaxf(m, __shfl_xor(m, 32));
            float ssum = 0.f;
            #pragma unroll
            for (int r = 0; r < 16; ++r) { p[r] = __expf(p[r] - m); ssum += p[r]; }
            ssum += __shfl_xor(ssum, 32);
            float inv = 1.f / ssum;
            #pragma unroll
            for (int r = 0; r < 16; ++r) { p[r] *= inv; acc[si][r] += p[r]; }

            // pack P -> pT[qv][kv] bf16
            unsigned* pTrow = (unsigned*)&pT[wid][l31][0];
            #pragma unroll
            for (int mm = 0; mm < 8; ++mm) {
                unsigned pk;
                asm("v_cvt_pk_bf16_f32 %0, %1, %2" : "=v"(pk) : "v"(p[2 * mm]), "v"(p[2 * mm + 1]));
                pTrow[(mm & 1) + 4 * (mm >> 1) + 2 * hi2] = pk;
            }

            // PV: xo^T[d][qv] = V^T * P^T
            bf16x8 vf = *(const bf16x8*)&vT[wid][l15][hi4 * 8];
            bf16x8 p1 = *(const bf16x8*)&pT[wid][l15][hi4 * 8];
            bf16x8 p2 = *(const bf16x8*)&pT[wid][16 + l15][hi4 * 8];
            f32x4 z4;
            #pragma unroll
            for (int i = 0; i < 4; ++i) z4[i] = 0.f;
            f32x4 xo1 = __builtin_amdgcn_mfma_f32_16x16x32_bf16(vf, p1, z4, 0, 0, 0);
            f32x4 xo2 = __builtin_amdgcn_mfma_f32_16x16x32_bf16(vf, p2, z4, 0, 0, 0);

            // lane holds 4 consecutive d for fixed qv -> b128 into xo tile [s][qv*16+d]
            int s_loc = wid * 4 + si;
            float* row = smem + s_loc * 516;
            *(f32x4*)(row + l15 * 16 + hi4 * 4) = xo1;
            *(f32x4*)(row + (16 + l15) * 16 + hi4 * 4) = xo2;

            if (si < 3) { q_c = q_n; k_c = k_n; v_c = v_n; }
        }
        __syncthreads();
        // sweep xo tile -> out[c][s] (this h), fully coalesced 64B rows
        {
            int rr = t >> 2, si4 = (t & 3) << 2;
            #pragma unroll
            for (int j = 0; j < 8; ++j) {
                int c_loc = j * 64 + rr;            // qv*16 + dk
                int qv = c_loc >> 4, dk = c_loc & 15;
                int c = (k_ * V_ + qv) * 64 + h * 16 + dk;
                float4 o;
                o.x = smem[(si4 + 0) * 516 + c_loc];
                o.y = smem[(si4 + 1) * 516 + c_loc];
                o.z = smem[(si4 + 2) * 516 + c_loc];
                o.w = smem[(si4 + 3) * 516 + c_loc];
                *(float4*)(out + ((size_t)b * 8192 + c) * S_ + s0 + stile0 + si4) = o;
            }
        }
        __syncthreads();   // tile free before next h (or att passes)
    }

    // attention-mean output: two 512-row passes through the same tile
    #pragma unroll
    for (int pass = 0; pass < 2; ++pass) {
        if (pass) __syncthreads();
        if ((l31 >> 4) == pass) {
            int qh = l31 & 15;
            #pragma unroll
            for (int si = 0; si < 4; ++si) {
                int s_loc = wid * 4 + si;
                int col = s_loc ^ qh;               // XOR swizzle: conflict-free writes
                #pragma unroll
                for (int r = 0; r < 16; ++r) {
                    int kv = (r & 3) + 8 * (r >> 2) + 4 * hi2;
                    smem[(qh * 32 + kv) * 16 + col] = 0.25f * acc[si][r];
                }
            }
        }
        __syncthreads();
        {
            int rr = t >> 2, si4 = (t & 3) << 2;
            #pragma unroll
            for (int j = 0; j < 8; ++j) {
                int prow = j * 64 + rr;
                int qh = prow >> 5;
                float4 o;
                o.x = smem[prow * 16 + ((si4 + 0) ^ qh)];
                o.y = smem[prow * 16 + ((si4 + 1) ^ qh)];
                o.z = smem[prow * 16 + ((si4 + 2) ^ qh)];
                o.w = smem[prow * 16 + ((si4 + 3) ^ qh)];
                int p = pass * 512 + prow;
                *(float4*)(out_am + ((size_t)bk * 1024 + p) * S_ + s0 + stile0 + si4) = o;
            }
        }
    }
}

// ---------------------------------------------------------------- launch
extern "C" void kernel_launch(void* const* d_in, const int* in_sizes, int n_in,
                              void* d_out, int out_size, void* d_ws, size_t ws_size,
                              hipStream_t stream) {
    const float* x = (const float*)d_in[0];
    const float* W = (const float*)d_in[1];
    const float* bias = (const float*)d_in[2];
    float* out = (float*)d_out;
    float* out_am = out + (size_t)33554432;   // xo is 4*8192*1024

    const size_t W2_BYTES = (size_t)24576 * 16 * 4;
    // chunk size SC over S: ws holds only the qkv chunk (bf16)
    int SC = 32;
    for (int cand = 512; cand >= 32; cand >>= 1) {
        size_t need = W2_BYTES + (size_t)16 * cand * 6144 * 2;
        if (need <= ws_size) { SC = cand; break; }
    }

    float* W2 = (float*)d_ws;
    __hip_bfloat16* qkv = (__hip_bfloat16*)((char*)d_ws + W2_BYTES);

    prep_w2_kernel<<<1536, 256, 0, stream>>>(W, W2);

    int ntile = SC / 32;
    for (int s0 = 0; s0 < S_; s0 += SC) {
        conv_kernel<<<dim3(16 * 3 * 4 * ntile), 256, 0, stream>>>(x, W2, bias, qkv, SC, s0, ntile);
        attn2_kernel<<<dim3(16 * (SC / 16)), 256, 0, stream>>>(qkv, out, out_am, SC, s0);
    }
}

// Round 3
// 203.424 us; speedup vs baseline: 1.5358x; 1.1286x over previous
//
#include <hip/hip_runtime.h>
#include <hip/hip_bf16.h>
#include <stdint.h>

#define SCALE 0.25f

typedef __attribute__((ext_vector_type(8))) short bf16x8;
typedef __attribute__((ext_vector_type(4))) float f32x4;
typedef __attribute__((ext_vector_type(16))) float f32x16;

// ---------------------------------------------------------------- W repack
// W[o][i][t] (15 floats/row) -> W2[o][16] padded (b128-friendly)
__global__ __launch_bounds__(256) void prep_w2_kernel(const float* __restrict__ W,
                                                      float* __restrict__ W2) {
    int idx = blockIdx.x * 256 + threadIdx.x;   // 24576*16 threads
    int o = idx >> 4, j = idx & 15;
    W2[idx] = (j < 15) ? W[o * 15 + j] : 0.f;
}

// ---------------------------------------------------------------- fully fused kernel
// block = (bk, 32 s), 512 threads (8 waves). Per h: conv(fp32)->qkv LDS (bf16,
// 16 s per half) -> attention (MFMA) -> xo tile [32 s][516] -> 128B-line sweep.
// attn-mean in regs over h, swizzled LDS tile, 128B-line sweep at the end.
//
// LDS layout (dynamic, 159744 B):
//   qkv_s : [16 s][3 c3][32 v][16 dk] bf16          @ 0       (49152)
//   xo_s  : [32 s][516] f32  (reused as att[512][32]) @ 49152  (66048)
//   vT    : [8 w][16 d][40] ushort                   @ 115200  (10240)
//   pT    : [8 w][32 qv][40] ushort                  @ 125440  (20480)
//   xs    : [96 ch][36 s] f32                        @ 145920  (13824)
#define QKV_OFF 0
#define XO_OFF 49152
#define VT_OFF 115200
#define PT_OFF 125440
#define XS_OFF 145920
#define LDS_TOTAL 159744

__global__ __launch_bounds__(512, 2) void fused_kernel(const float* __restrict__ x,
                                                       const float* __restrict__ W2,
                                                       const float* __restrict__ bias,
                                                       float* __restrict__ out,
                                                       float* __restrict__ out_am) {
    extern __shared__ char smraw[];
    __hip_bfloat16* qkv_s = (__hip_bfloat16*)(smraw + QKV_OFF);
    float* xo_s = (float*)(smraw + XO_OFF);
    unsigned short* vT = (unsigned short*)(smraw + VT_OFF);
    unsigned short* pT = (unsigned short*)(smraw + PT_OFF);
    float* xs = (float*)(smraw + XS_OFF);

    int bk = blockIdx.x >> 5, st = blockIdx.x & 31;
    int b = bk >> 2, k_ = bk & 3;
    int t = threadIdx.x;
    int wid = t >> 6, lane = t & 63;
    int l31 = lane & 31, hi2 = lane >> 5;
    int l15 = lane & 15, hi4 = lane >> 4;

    // ---- load x window [96 ch][36 s] (once per block; h-independent)
    {
        int sbase = st * 32 - 4;
        #pragma unroll
        for (int i = 0; i < 7; ++i) {
            int idx = i * 512 + t;
            if (idx < 3456) {
                int row = idx / 36, col = idx - row * 36;
                int sg = sbase + col;
                xs[idx] = (sg >= 0) ? x[((size_t)b * 384 + k_ * 96 + row) * 1024 + sg] : 0.f;
            }
        }
    }

    int v = t >> 4, dk = t & 15;
    int g3 = (k_ * 32 + v) * 3;

    float acc_am[4][16];
    #pragma unroll
    for (int a = 0; a < 4; ++a)
        #pragma unroll
        for (int r = 0; r < 16; ++r) acc_am[a][r] = 0.f;

    for (int h = 0; h < 4; ++h) {
        // ---- per-h weights: 3 rows (q,k,v channel for this (v,dk)) x 15 taps
        float w[3][16];
        float bs[3];
        #pragma unroll
        for (int c3 = 0; c3 < 3; ++c3) {
            int row = (g3 + c3) * 64 + h * 16 + dk;
            const float4* p = (const float4*)(W2 + (size_t)row * 16);
            float4 a0 = p[0], a1 = p[1], a2 = p[2], a3 = p[3];
            w[c3][0] = a0.x;  w[c3][1] = a0.y;  w[c3][2] = a0.z;  w[c3][3] = a0.w;
            w[c3][4] = a1.x;  w[c3][5] = a1.y;  w[c3][6] = a1.z;  w[c3][7] = a1.w;
            w[c3][8] = a2.x;  w[c3][9] = a2.y;  w[c3][10] = a2.z; w[c3][11] = a2.w;
            w[c3][12] = a3.x; w[c3][13] = a3.y; w[c3][14] = a3.z; w[c3][15] = a3.w;
            bs[c3] = bias[row];
        }

        for (int half = 0; half < 2; ++half) {
            __syncthreads();   // qkv tile (and xs on first iter) safe to (re)use

            // ---- conv: 16 s x 3 c3 outputs for this thread's (v,dk), h-slice
            #pragma unroll
            for (int sb = 0; sb < 2; ++sb) {
                float xw[3][12];
                #pragma unroll
                for (int i = 0; i < 3; ++i)
                    #pragma unroll
                    for (int j = 0; j < 12; ++j)
                        xw[i][j] = xs[(v * 3 + i) * 36 + half * 16 + sb * 8 + j];
                #pragma unroll
                for (int s8 = 0; s8 < 8; ++s8) {
                    #pragma unroll
                    for (int c3 = 0; c3 < 3; ++c3) {
                        float a = bs[c3];
                        #pragma unroll
                        for (int i = 0; i < 3; ++i)
                            #pragma unroll
                            for (int tt = 0; tt < 5; ++tt)
                                a = fmaf(xw[i][s8 + tt], w[c3][i * 5 + tt], a);
                        qkv_s[((sb * 8 + s8) * 3 + c3) * 512 + v * 16 + dk] =
                            __float2bfloat16(a);
                    }
                }
            }
            __syncthreads();   // qkv tile ready

            // ---- attention: 2 s per wave
            #pragma unroll
            for (int jj = 0; jj < 2; ++jj) {
                int s_tile = wid * 2 + jj;
                int s_loc = half * 16 + s_tile;
                const __hip_bfloat16* qb = qkv_s + (s_tile * 3) * 512 + l31 * 16 + hi2 * 8;
                bf16x8 qf = *(const bf16x8*)qb;
                bf16x8 kf = *(const bf16x8*)(qb + 512);
                uint4 vv = *(const uint4*)(qb + 1024);

                // stage V transposed (wave-private): vT[d][kv]
                {
                    const unsigned short* us = (const unsigned short*)&vv;
                    #pragma unroll
                    for (int j = 0; j < 8; ++j)
                        vT[(wid * 16 + hi2 * 8 + j) * 40 + l31] = us[j];
                }

                // logits = K * Q^T : D[kv][qv]
                f32x16 zc;
                #pragma unroll
                for (int i = 0; i < 16; ++i) zc[i] = 0.f;
                f32x16 lg = __builtin_amdgcn_mfma_f32_32x32x16_bf16(kf, qf, zc, 0, 0, 0);

                // softmax over kv (lane holds 16 kv-rows of column qv=l31)
                float p[16], m = -3.0e38f;
                #pragma unroll
                for (int r = 0; r < 16; ++r) { p[r] = lg[r] * SCALE; m = fmaxf(m, p[r]); }
                m = fmaxf(m, __shfl_xor(m, 32));
                float ssum = 0.f;
                #pragma unroll
                for (int r = 0; r < 16; ++r) { p[r] = __expf(p[r] - m); ssum += p[r]; }
                ssum += __shfl_xor(ssum, 32);
                float inv = 1.f / ssum;
                int a_idx = half * 2 + jj;
                #pragma unroll
                for (int r = 0; r < 16; ++r) { p[r] *= inv; acc_am[a_idx][r] += p[r]; }

                // pack P -> pT[qv][kv] bf16
                unsigned* pTrow = (unsigned*)&pT[(wid * 32 + l31) * 40];
                #pragma unroll
                for (int mm = 0; mm < 8; ++mm) {
                    unsigned pk;
                    asm("v_cvt_pk_bf16_f32 %0, %1, %2"
                        : "=v"(pk) : "v"(p[2 * mm]), "v"(p[2 * mm + 1]));
                    pTrow[(mm & 1) + 4 * (mm >> 1) + 2 * hi2] = pk;
                }

                // PV: xo^T[d][qv] = V^T * P^T
                bf16x8 vf = *(const bf16x8*)&vT[(wid * 16 + l15) * 40 + hi4 * 8];
                bf16x8 p1 = *(const bf16x8*)&pT[(wid * 32 + l15) * 40 + hi4 * 8];
                bf16x8 p2 = *(const bf16x8*)&pT[(wid * 32 + 16 + l15) * 40 + hi4 * 8];
                f32x4 z4;
                #pragma unroll
                for (int i = 0; i < 4; ++i) z4[i] = 0.f;
                f32x4 xo1 = __builtin_amdgcn_mfma_f32_16x16x32_bf16(vf, p1, z4, 0, 0, 0);
                f32x4 xo2 = __builtin_amdgcn_mfma_f32_16x16x32_bf16(vf, p2, z4, 0, 0, 0);

                // xo tile row s_loc, col = qv*16 + d (4 consecutive d per frag)
                float* row = xo_s + s_loc * 516;
                *(f32x4*)(row + l15 * 16 + hi4 * 4) = xo1;
                *(f32x4*)(row + (16 + l15) * 16 + hi4 * 4) = xo2;
            }
        }
        __syncthreads();   // all 32 xo rows written

        // ---- sweep xo -> out[c][s], full 128B lines (8 lanes per c-row)
        #pragma unroll
        for (int j = 0; j < 8; ++j) {
            int c_loc = j * 64 + (t >> 3);
            int s4 = (t & 7) * 4;
            float4 o;
            o.x = xo_s[(s4 + 0) * 516 + c_loc];
            o.y = xo_s[(s4 + 1) * 516 + c_loc];
            o.z = xo_s[(s4 + 2) * 516 + c_loc];
            o.w = xo_s[(s4 + 3) * 516 + c_loc];
            int c = k_ * 2048 + (c_loc >> 4) * 64 + h * 16 + (c_loc & 15);
            *(float4*)(out + ((size_t)b * 8192 + c) * 1024 + st * 32 + s4) = o;
        }
    }

    // ---- attention-mean: att[512 rows][32 s] tile (reuses xo region), 2 passes
    float* att = xo_s;
    #pragma unroll
    for (int pass = 0; pass < 2; ++pass) {
        __syncthreads();   // region free (sweep / previous pass done)
        if ((l31 >> 4) == pass) {
            int qh = l31 & 15;
            #pragma unroll
            for (int a = 0; a < 4; ++a) {
                int s_loc = (a >> 1) * 16 + wid * 2 + (a & 1);
                int col = s_loc ^ qh;     // XOR swizzle: conflict-free writes
                #pragma unroll
                for (int r = 0; r < 16; ++r) {
                    int kv = (r & 3) + 8 * (r >> 2) + 4 * hi2;
                    att[(qh * 32 + kv) * 32 + col] = 0.25f * acc_am[a][r];
                }
            }
        }
        __syncthreads();
        #pragma unroll
        for (int j = 0; j < 8; ++j) {
            int tr = j * 64 + (t >> 3);
            int qh = tr >> 5;
            int s4 = (t & 7) * 4;
            float4 o;
            o.x = att[tr * 32 + ((s4 + 0) ^ qh)];
            o.y = att[tr * 32 + ((s4 + 1) ^ qh)];
            o.z = att[tr * 32 + ((s4 + 2) ^ qh)];
            o.w = att[tr * 32 + ((s4 + 3) ^ qh)];
            *(float4*)(out_am + ((size_t)bk * 1024 + pass * 512 + tr) * 1024 + st * 32 + s4) = o;
        }
    }
}

// ---------------------------------------------------------------- launch
extern "C" void kernel_launch(void* const* d_in, const int* in_sizes, int n_in,
                              void* d_out, int out_size, void* d_ws, size_t ws_size,
                              hipStream_t stream) {
    const float* x = (const float*)d_in[0];
    const float* W = (const float*)d_in[1];
    const float* bias = (const float*)d_in[2];
    float* out = (float*)d_out;
    float* out_am = out + (size_t)33554432;   // xo is 4*8192*1024

    float* W2 = (float*)d_ws;                 // 24576*16*4 = 1.5 MB

    // allow >64KB dynamic LDS (idempotent; safe outside/inside capture)
    static int attr_set = 0;
    (void)hipFuncSetAttribute((const void*)fused_kernel,
                              hipFuncAttributeMaxDynamicSharedMemorySize, LDS_TOTAL);
    (void)attr_set;

    prep_w2_kernel<<<1536, 256, 0, stream>>>(W, W2);
    fused_kernel<<<512, 512, LDS_TOTAL, stream>>>(x, W2, bias, out, out_am);
}

// Round 4
// 121.100 us; speedup vs baseline: 2.5799x; 1.6798x over previous
//
#include <hip/hip_runtime.h>
#include <hip/hip_bf16.h>
#include <stdint.h>

#define SCALE 0.25f

typedef __attribute__((ext_vector_type(8))) short bf16x8;
typedef __attribute__((ext_vector_type(4))) float f32x4;
typedef __attribute__((ext_vector_type(16))) float f32x16;

// ---------------------------------------------------------------- W repack
__global__ __launch_bounds__(256) void prep_w2_kernel(const float* __restrict__ W,
                                                      float* __restrict__ W2) {
    int idx = blockIdx.x * 256 + threadIdx.x;   // 24576*16 threads
    int o = idx >> 4, j = idx & 15;
    W2[idx] = (j < 15) ? W[o * 15 + j] : 0.f;
}

// ---------------------------------------------------------------- fused, pipelined
// block = (bk, 32 s), 512 threads (8 waves). 16 stages (h,q): per stage
// {attn(k) || conv(k+1) || sweep(k-1)} + ONE barrier. qkv and xo double-buffered.
//
// LDS (dynamic, 126976 B):
//   xs   @0      : [96][36] f32                       13824
//   qkv0 @13824  : [8 s][3][512] bf16                 24576
//   qkv1 @38400  :                                    24576
//   xo0  @62976  : [8 s][520] f32                     16640
//   xo1  @79616  :                                    16640
//   vT   @96256  : [8 w][16][40] ushort               10240
//   pT   @106496 : [8 w][32][40] ushort               20480
//   att  @0      : [512][36] f32 (reuses xs..xo0 after main loop)  73728
#define LDS_TOTAL 126976

__global__ __launch_bounds__(512, 2) void fused2_kernel(const float* __restrict__ x,
                                                        const float* __restrict__ W2,
                                                        const float* __restrict__ bias,
                                                        float* __restrict__ out,
                                                        float* __restrict__ out_am) {
    extern __shared__ char smraw[];
    float* xs = (float*)smraw;
    char* qkvbuf0 = smraw + 13824;
    char* qkvbuf1 = smraw + 38400;
    float* xobuf0 = (float*)(smraw + 62976);
    float* xobuf1 = (float*)(smraw + 79616);
    unsigned short* vT = (unsigned short*)(smraw + 96256);
    unsigned short* pT = (unsigned short*)(smraw + 106496);
    float* att = (float*)smraw;

    // XCD-aware decode: same-k_ blocks share 2 XCD slots -> W2 slice L2-resident
    {
    }
    int bi = blockIdx.x, slot = bi & 7, jj = bi >> 3;
    int k_ = slot >> 1, b = jj >> 4, st = ((slot & 1) << 4) | (jj & 15);
    int bk = b * 4 + k_;

    int t = threadIdx.x;
    int wid = t >> 6, lane = t & 63;
    int l31 = lane & 31, hi2 = lane >> 5;
    int l15 = lane & 15, hi4 = lane >> 4;

    // ---- x window [96 ch][36 s]
    {
        int sbase = st * 32 - 4;
        #pragma unroll
        for (int i = 0; i < 7; ++i) {
            int idx = i * 512 + t;
            if (idx < 3456) {
                int row = idx / 36, col = idx - row * 36;
                int sg = sbase + col;
                xs[idx] = (sg >= 0) ? x[((size_t)b * 384 + k_ * 96 + row) * 1024 + sg] : 0.f;
            }
        }
    }

    int v = t >> 4, dk = t & 15;
    int g3 = (k_ * 32 + v) * 3;

    float w[3][16], bs[3];
    auto loadw = [&](int hh) {
        #pragma unroll
        for (int c3 = 0; c3 < 3; ++c3) {
            int row = (g3 + c3) * 64 + hh * 16 + dk;
            const float4* p = (const float4*)(W2 + (size_t)row * 16);
            float4 a0 = p[0], a1 = p[1], a2 = p[2], a3 = p[3];
            w[c3][0] = a0.x;  w[c3][1] = a0.y;  w[c3][2] = a0.z;  w[c3][3] = a0.w;
            w[c3][4] = a1.x;  w[c3][5] = a1.y;  w[c3][6] = a1.z;  w[c3][7] = a1.w;
            w[c3][8] = a2.x;  w[c3][9] = a2.y;  w[c3][10] = a2.z; w[c3][11] = a2.w;
            w[c3][12] = a3.x; w[c3][13] = a3.y; w[c3][14] = a3.z; w[c3][15] = a3.w;
            bs[c3] = bias[row];
        }
    };

    auto conv_stage = [&](int qs, char* dstraw) {
        __hip_bfloat16* dst = (__hip_bfloat16*)dstraw;
        float xw[3][12];
        #pragma unroll
        for (int i = 0; i < 3; ++i)
            #pragma unroll
            for (int j = 0; j < 12; ++j)
                xw[i][j] = xs[(v * 3 + i) * 36 + qs * 8 + j];
        #pragma unroll
        for (int s8 = 0; s8 < 8; ++s8) {
            #pragma unroll
            for (int c3 = 0; c3 < 3; ++c3) {
                float a = bs[c3];
                #pragma unroll
                for (int i = 0; i < 3; ++i)
                    #pragma unroll
                    for (int tt = 0; tt < 5; ++tt)
                        a = fmaf(xw[i][s8 + tt], w[c3][i * 5 + tt], a);
                dst[(s8 * 3 + c3) * 512 + v * 16 + dk] = __float2bfloat16(a);
            }
        }
    };

    auto sweep_stage = [&](int hp, int qp, const float* xo) {
        int c_loc = t;
        int qv = c_loc >> 4, dkc = c_loc & 15;
        int col = c_loc ^ (4 * (qv & 7));
        float o0 = xo[0 * 520 + col], o1 = xo[1 * 520 + col];
        float o2 = xo[2 * 520 + col], o3 = xo[3 * 520 + col];
        float o4 = xo[4 * 520 + col], o5 = xo[5 * 520 + col];
        float o6 = xo[6 * 520 + col], o7 = xo[7 * 520 + col];
        int c = k_ * 2048 + qv * 64 + hp * 16 + dkc;
        float* base = out + ((size_t)b * 8192 + c) * 1024 + st * 32 + qp * 8;
        float4 A; A.x = o0; A.y = o1; A.z = o2; A.w = o3;
        float4 Bv; Bv.x = o4; Bv.y = o5; Bv.z = o6; Bv.w = o7;
        *(float4*)base = A;
        *(float4*)(base + 4) = Bv;
    };

    float acc_am[4][16];
    #pragma unroll
    for (int a = 0; a < 4; ++a)
        #pragma unroll
        for (int r = 0; r < 16; ++r) acc_am[a][r] = 0.f;

    // ---- prologue: weights h=0, conv stage (0,0) -> qkv0
    loadw(0);
    __syncthreads();            // xs ready (loaded above)
    conv_stage(0, qkvbuf0);
    __syncthreads();

    for (int h = 0; h < 4; ++h) {
        #pragma unroll
        for (int q = 0; q < 4; ++q) {
            // early weight issue for next h (regs not used by attn)
            if (q == 3 && h < 3) loadw(h + 1);

            // ---------------- attn(h,q): reads qkv[q&1], writes xo[q&1]
            {
                char* qbuf = (q & 1) ? qkvbuf1 : qkvbuf0;
                float* xo = (q & 1) ? xobuf1 : xobuf0;
                const __hip_bfloat16* qb =
                    (const __hip_bfloat16*)qbuf + (wid * 3) * 512 + l31 * 16 + hi2 * 8;
                bf16x8 qf = *(const bf16x8*)qb;
                bf16x8 kf = *(const bf16x8*)(qb + 512);
                uint4 vv = *(const uint4*)(qb + 1024);

                {   // vT scatter [d][kv]
                    const unsigned short* us = (const unsigned short*)&vv;
                    #pragma unroll
                    for (int j = 0; j < 8; ++j)
                        vT[(wid * 16 + hi2 * 8 + j) * 40 + l31] = us[j];
                }

                f32x16 zc;
                #pragma unroll
                for (int i = 0; i < 16; ++i) zc[i] = 0.f;
                f32x16 lg = __builtin_amdgcn_mfma_f32_32x32x16_bf16(kf, qf, zc, 0, 0, 0);

                float p[16], m = -3.0e38f;
                #pragma unroll
                for (int r = 0; r < 16; ++r) { p[r] = lg[r] * SCALE; m = fmaxf(m, p[r]); }
                m = fmaxf(m, __shfl_xor(m, 32));
                float ssum = 0.f;
                #pragma unroll
                for (int r = 0; r < 16; ++r) { p[r] = __expf(p[r] - m); ssum += p[r]; }
                ssum += __shfl_xor(ssum, 32);
                float inv = 1.f / ssum;
                #pragma unroll
                for (int r = 0; r < 16; ++r) { p[r] *= inv; acc_am[q][r] += p[r]; }

                // pT [qv][kv] bf16, write-swizzled (dword idx ^ 4*(qv>>3))
                unsigned* pTrow = (unsigned*)(pT + (size_t)(wid * 32 + l31) * 40);
                int wsw = (l31 >> 3) & 1 ? 4 : 0;
                #pragma unroll
                for (int mm = 0; mm < 8; ++mm) {
                    unsigned pk;
                    asm("v_cvt_pk_bf16_f32 %0, %1, %2"
                        : "=v"(pk) : "v"(p[2 * mm]), "v"(p[2 * mm + 1]));
                    pTrow[((mm & 1) + 4 * (mm >> 1) + 2 * hi2) ^ wsw] = pk;
                }

                int rsw = (l15 >> 3) & 1 ? 8 : 0;   // ushort-offset XOR (== dword ^4)
                bf16x8 vf = *(const bf16x8*)&vT[(wid * 16 + l15) * 40 + hi4 * 8];
                bf16x8 p1 = *(const bf16x8*)&pT[(wid * 32 + l15) * 40 + (hi4 * 8 ^ rsw)];
                bf16x8 p2 = *(const bf16x8*)&pT[(wid * 32 + 16 + l15) * 40 + (hi4 * 8 ^ rsw)];
                f32x4 z4;
                #pragma unroll
                for (int i = 0; i < 4; ++i) z4[i] = 0.f;
                f32x4 xo1 = __builtin_amdgcn_mfma_f32_16x16x32_bf16(vf, p1, z4, 0, 0, 0);
                f32x4 xo2 = __builtin_amdgcn_mfma_f32_16x16x32_bf16(vf, p2, z4, 0, 0, 0);

                // xo tile row wid, col (qv*16 + d) ^ 4*(qv&7)
                float* row = xo + wid * 520;
                int sw = 4 * (l15 & 7);
                *(f32x4*)(row + ((l15 * 16 + hi4 * 4) ^ sw)) = xo1;
                *(f32x4*)(row + (((16 + l15) * 16 + hi4 * 4) ^ sw)) = xo2;
            }

            // ---------------- conv(k+1) -> qkv[(q+1)&1]
            if (!(h == 3 && q == 3)) {
                conv_stage((q + 1) & 3, ((q + 1) & 1) ? qkvbuf1 : qkvbuf0);
            }

            // ---------------- sweep(k-1): xo[(q+1)&1] -> out
            if (!(h == 0 && q == 0)) {
                int hp = (q == 0) ? h - 1 : h;
                sweep_stage(hp, (q + 3) & 3, ((q + 1) & 1) ? xobuf1 : xobuf0);
            }

            __syncthreads();
        }
    }
    // epilogue sweep (3,3)
    sweep_stage(3, 3, xobuf1);
    __syncthreads();

    // ---------------- attn-mean: att[512][36] tile, 2 passes over qv halves
    #pragma unroll
    for (int pass = 0; pass < 2; ++pass) {
        if (pass) __syncthreads();
        if ((l31 >> 4) == pass) {
            int qh = l31 & 15;
            int csw = 4 * (qh & 7);
            #pragma unroll
            for (int q = 0; q < 4; ++q) {
                int sp = q * 8 + wid;
                int colp = sp ^ csw;
                #pragma unroll
                for (int r = 0; r < 16; ++r) {
                    int kv = (r & 3) + 8 * (r >> 2) + 4 * hi2;
                    att[(qh * 32 + kv) * 36 + colp] = 0.25f * acc_am[q][r];
                }
            }
        }
        __syncthreads();
        #pragma unroll
        for (int j = 0; j < 8; ++j) {
            int tr = j * 64 + (t >> 3);
            int csw = 4 * ((tr >> 5) & 7);
            int s4 = (t & 7) * 4;
            float4 o;
            o.x = att[tr * 36 + ((s4 + 0) ^ csw)];
            o.y = att[tr * 36 + ((s4 + 1) ^ csw)];
            o.z = att[tr * 36 + ((s4 + 2) ^ csw)];
            o.w = att[tr * 36 + ((s4 + 3) ^ csw)];
            *(float4*)(out_am + ((size_t)bk * 1024 + pass * 512 + tr) * 1024 + st * 32 + s4) = o;
        }
    }
}

// ---------------------------------------------------------------- launch
extern "C" void kernel_launch(void* const* d_in, const int* in_sizes, int n_in,
                              void* d_out, int out_size, void* d_ws, size_t ws_size,
                              hipStream_t stream) {
    const float* x = (const float*)d_in[0];
    const float* W = (const float*)d_in[1];
    const float* bias = (const float*)d_in[2];
    float* out = (float*)d_out;
    float* out_am = out + (size_t)33554432;   // xo is 4*8192*1024

    float* W2 = (float*)d_ws;                 // 24576*16*4 = 1.5 MB

    (void)hipFuncSetAttribute((const void*)fused2_kernel,
                              hipFuncAttributeMaxDynamicSharedMemorySize, LDS_TOTAL);

    prep_w2_kernel<<<1536, 256, 0, stream>>>(W, W2);
    fused2_kernel<<<512, 512, LDS_TOTAL, stream>>>(x, W2, bias, out, out_am);
}